// Round 3
// baseline (5683.931 us; speedup 1.0000x reference)
//
#include <hip/hip_runtime.h>
#include <hip/hip_bf16.h>
#include <math.h>

#define B_SZ 16384
#define T_CONV 8
#define HID 256
#define CHUNK 8192

__device__ __forceinline__ float sigm(float x) { return 1.f / (1.f + expf(-x)); }

// ---------------------------------------------------------------------------
// Feature kernel: embeddings -> nv -> conv(elu) -> x (B*8, 59)
// 4 samples per 256-thread block; conv_w staged in LDS.
// ---------------------------------------------------------------------------
#define FB_SAMPLES 4
__global__ __launch_bounds__(256) void feature_kernel(
    const int* __restrict__ region_idx, const int* __restrict__ poi_idx,
    const int* __restrict__ car_idx, const int* __restrict__ week_idx,
    const int* __restrict__ time_idx, const float* __restrict__ coords,
    const float* __restrict__ region_tbl, const float* __restrict__ poi_tbl,
    const float* __restrict__ car_tbl, const float* __restrict__ week_tbl,
    const float* __restrict__ time_tbl, const float* __restrict__ W_rp,
    const float* __restrict__ b_rp, const float* __restrict__ W_co,
    const float* __restrict__ b_co, const float* __restrict__ conv_w,
    const float* __restrict__ conv_b, float* __restrict__ X)
{
    __shared__ float s_cw[3 * 40 * 32];
    __shared__ float s_nv[FB_SAMPLES][10][40];
    __shared__ float s_emb[FB_SAMPLES][27];
    __shared__ float s_rp[FB_SAMPLES][10][12];

    int tid = threadIdx.x;
    for (int i = tid; i < 3840; i += 256) s_cw[i] = conv_w[i];

    int s  = tid >> 6;
    int lt = tid & 63;
    int b  = blockIdx.x * FB_SAMPLES + s;

    if (lt < 27) {
        float v;
        if (lt < 16)      v = car_tbl[(size_t)car_idx[b] * 16 + lt];
        else if (lt < 19) v = week_tbl[week_idx[b] * 3 + (lt - 16)];
        else              v = time_tbl[time_idx[b] * 8 + (lt - 19)];
        s_emb[s][lt] = tanhf(v);
    }
    for (int i = lt; i < 120; i += 64) {
        int t = i / 12, k = i % 12;
        float v;
        if (k < 8) v = region_tbl[(size_t)region_idx[b * 10 + t] * 8 + k];
        else       v = poi_tbl[poi_idx[b * 10 + t] * 4 + (k - 8)];
        s_rp[s][t][k] = v;
    }
    __syncthreads();

    for (int i = lt; i < 400; i += 64) {
        int t = i / 40, j = i % 40;
        float acc;
        if (j < 32) {
            acc = b_rp[j];
            #pragma unroll
            for (int k = 0; k < 12; k++) acc += s_rp[s][t][k] * W_rp[k * 32 + j];
        } else {
            int j2 = j - 32;
            acc = b_co[j2] + coords[(size_t)(b * 10 + t) * 2 + 0] * W_co[j2]
                           + coords[(size_t)(b * 10 + t) * 2 + 1] * W_co[8 + j2];
        }
        s_nv[s][t][j] = acc;
    }
    __syncthreads();

    // conv (t=0..7, 32 outs) + elu, write to X cols 0..31
    for (int i = lt; i < 256; i += 64) {
        int t = i >> 5, o = i & 31;
        float acc = conv_b[o];
        #pragma unroll
        for (int dt = 0; dt < 3; dt++)
            #pragma unroll
            for (int c = 0; c < 40; c++)
                acc += s_nv[s][t + dt][c] * s_cw[(dt * 40 + c) * 32 + o];
        acc = acc > 0.f ? acc : expm1f(acc);
        X[(size_t)(b * 8 + t) * 59 + o] = acc;
    }
    // emb broadcast, X cols 32..58
    for (int i = lt; i < 216; i += 64) {
        int t = i / 27, j = i % 27;
        X[(size_t)(b * 8 + t) * 59 + 32 + j] = s_emb[s][j];
    }
}

// ---------------------------------------------------------------------------
// Dual GEMM: C[m,n] = sum_k A1[m,k]*B1[n,k] + sum_k A2[m,k]*B2[n,k] + bias[n]
// (A2 may be null). Tiles: BM=128, BN=64, BK=32. 256 threads, 8x4 per thread.
// M % 128 == 0, N % 64 == 0 required (always true here). K guarded.
// ---------------------------------------------------------------------------
#define BM 128
#define BN 64
#define BK 32
__global__ __launch_bounds__(256) void gemm_dual(
    const float* __restrict__ A1, int lda1, int K1, const float* __restrict__ B1, int ldb1,
    const float* __restrict__ A2, int lda2, int K2, const float* __restrict__ B2, int ldb2,
    const float* __restrict__ bias, float* __restrict__ C, int ldc, int M, int N)
{
    __shared__ float As[BK][BM + 4];   // [k][m]
    __shared__ float Bs[BK][BN + 4];   // [k][n]

    int tid = threadIdx.x;
    int tx = tid & 15, ty = tid >> 4;
    int bm = blockIdx.y * BM, bn = blockIdx.x * BN;

    float acc[8][4] = {};

    for (int p = 0; p < 2; p++) {
        const float* A  = p ? A2 : A1;
        if (!A) continue;
        const float* Bw = p ? B2 : B1;
        int K   = p ? K2 : K1;
        int lda = p ? lda2 : lda1;
        int ldb = p ? ldb2 : ldb1;

        for (int k0 = 0; k0 < K; k0 += BK) {
            int col  = tid & 31;   // k within tile
            int row0 = tid >> 5;   // 8 rows per pass
            int k    = k0 + col;
            #pragma unroll
            for (int r = 0; r < 16; r++) {
                int row = row0 + r * 8;
                As[col][row] = (k < K) ? A[(size_t)(bm + row) * lda + k] : 0.f;
            }
            #pragma unroll
            for (int r = 0; r < 8; r++) {
                int row = row0 + r * 8;
                Bs[col][row] = (k < K) ? Bw[(size_t)(bn + row) * ldb + k] : 0.f;
            }
            __syncthreads();

            #pragma unroll
            for (int kk = 0; kk < BK; kk++) {
                float4 a0 = *(const float4*)&As[kk][ty * 8];
                float4 a1 = *(const float4*)&As[kk][ty * 8 + 4];
                float4 b0 = *(const float4*)&Bs[kk][tx * 4];
                float a[8] = {a0.x, a0.y, a0.z, a0.w, a1.x, a1.y, a1.z, a1.w};
                float bb[4] = {b0.x, b0.y, b0.z, b0.w};
                #pragma unroll
                for (int i = 0; i < 8; i++)
                    #pragma unroll
                    for (int j = 0; j < 4; j++)
                        acc[i][j] += a[i] * bb[j];
            }
            __syncthreads();
        }
    }

    #pragma unroll
    for (int i = 0; i < 8; i++) {
        int m = bm + ty * 8 + i;
        #pragma unroll
        for (int j = 0; j < 4; j++) {
            int n = bn + tx * 4 + j;
            float v = acc[i][j] + (bias ? bias[n] : 0.f);
            C[(size_t)m * ldc + n] = v;
        }
    }
}

// ---------------------------------------------------------------------------
// LSTM pointwise: gates (Bc,1024) -> c (in-place), h_out
// ---------------------------------------------------------------------------
__global__ __launch_bounds__(256) void lstm_pointwise(
    const float* __restrict__ GT, int ldg, float* __restrict__ c,
    float* __restrict__ h_out, int ld_h, int is_t0)
{
    int idx = blockIdx.x * 256 + threadIdx.x;
    int b = idx >> 8, j = idx & 255;
    const float* g = GT + (size_t)b * ldg;
    float gi = g[j], gf = g[256 + j], gg = g[512 + j], go = g[768 + j];
    float cold = is_t0 ? 0.f : c[idx];
    float cn = sigm(gf) * cold + sigm(gi) * tanhf(gg);
    float hn = sigm(go) * tanhf(cn);
    c[idx] = cn;
    h_out[(size_t)b * ld_h + j] = hn;
}

// ---------------------------------------------------------------------------
// Small helpers (weight collapse, run once per launch; negligible work)
// ---------------------------------------------------------------------------
__global__ void naive_ab(const float* __restrict__ A, int lda,
                         const float* __restrict__ Bm, int ldb,
                         const float* __restrict__ bias, float* __restrict__ C,
                         int M, int N, int K)
{
    int idx = blockIdx.x * 256 + threadIdx.x;
    if (idx >= M * N) return;
    int m = idx / N, n = idx % N;
    float acc = bias ? bias[n] : 0.f;
    for (int k = 0; k < K; k++) acc += A[(size_t)m * lda + k] * Bm[(size_t)k * ldb + n];
    C[idx] = acc;
}

__global__ void transpose_k(const float* __restrict__ A, int M, int N, float* __restrict__ AT)
{
    int idx = blockIdx.x * 256 + threadIdx.x;
    if (idx >= M * N) return;
    int m = idx / N, n = idx % N;
    AT[(size_t)n * M + m] = A[idx];
}

__global__ void add_vec(const float* __restrict__ a, const float* __restrict__ b,
                        float* __restrict__ c, int n)
{
    int i = blockIdx.x * 256 + threadIdx.x;
    if (i < n) c[i] = a[i] + b[i];
}

// ---------------------------------------------------------------------------
extern "C" void kernel_launch(void* const* d_in, const int* in_sizes, int n_in,
                              void* d_out, int out_size, void* d_ws, size_t ws_size,
                              hipStream_t stream)
{
    const int*   region_idx = (const int*)d_in[0];
    const int*   poi_idx    = (const int*)d_in[1];
    const int*   car_idx    = (const int*)d_in[2];
    const int*   week_idx   = (const int*)d_in[3];
    const int*   time_idx   = (const int*)d_in[4];
    const float* coords     = (const float*)d_in[5];
    const float* region_tbl = (const float*)d_in[6];
    const float* poi_tbl    = (const float*)d_in[7];
    const float* car_tbl    = (const float*)d_in[8];
    const float* week_tbl   = (const float*)d_in[9];
    const float* time_tbl   = (const float*)d_in[10];
    const float* W_rp   = (const float*)d_in[11];
    const float* b_rp   = (const float*)d_in[12];
    const float* W_co   = (const float*)d_in[13];
    const float* b_co   = (const float*)d_in[14];
    const float* conv_w = (const float*)d_in[15];
    const float* conv_b = (const float*)d_in[16];
    const float* Wih0 = (const float*)d_in[17];
    const float* Whh0 = (const float*)d_in[18];
    const float* bih0 = (const float*)d_in[19];
    const float* bhh0 = (const float*)d_in[20];
    const float* Wih1 = (const float*)d_in[21];
    const float* Whh1 = (const float*)d_in[22];
    const float* bih1 = (const float*)d_in[23];
    const float* bhh1 = (const float*)d_in[24];
    const float* W1 = (const float*)d_in[25];
    const float* b1 = (const float*)d_in[26];
    const float* W2 = (const float*)d_in[27];
    const float* b2 = (const float*)d_in[28];
    const float* W3 = (const float*)d_in[29];
    const float* b3 = (const float*)d_in[30];
    float* out = (float*)d_out;

    // ---- workspace layout (~96 MB total; GT lives in d_out) ----
    char* ws = (char*)d_ws;
    size_t off = 0;
    auto alloc = [&](size_t bytes) -> char* {
        char* p = ws + off;
        off = (off + bytes + 255) & ~(size_t)255;
        return p;
    };
    float* X      = (float*)alloc((size_t)B_SZ * 8 * 59 * 4);    // 29.5 MB
    float* h0     = (float*)alloc((size_t)B_SZ * HID * 4);       // 16 MB
    float* c0     = (float*)alloc((size_t)B_SZ * HID * 4);
    float* h1     = (float*)alloc((size_t)B_SZ * HID * 4);
    float* c1     = (float*)alloc((size_t)B_SZ * HID * 4);
    float* T1     = (float*)alloc(256 * 1024 * 4);               // W1@W2
    float* tb1    = (float*)alloc(1024 * 4);
    float* Wcomb  = (float*)alloc(256 * 512 * 4);
    float* WcombT = (float*)alloc(512 * 256 * 4);
    float* bcomb  = (float*)alloc(512 * 4);
    float* bias0  = (float*)alloc(1024 * 4);
    float* bias1  = (float*)alloc(1024 * 4);
    (void)ws_size;

    // Gate buffer: d_out is dead until the final head GEMM, and
    // 16384*512 == 8192*1024 floats == exactly one batch-chunk of gates.
    float* GT = out;

    // ---- collapse the linear head: Wcomb = W1@W2@W3, bcomb = (b1@W2+b2)@W3+b3
    naive_ab<<<(256 * 1024 + 255) / 256, 256, 0, stream>>>(W1, 512, W2, 1024, nullptr, T1, 256, 1024, 512);
    naive_ab<<<(1024 + 255) / 256, 256, 0, stream>>>(b1, 512, W2, 1024, b2, tb1, 1, 1024, 512);
    naive_ab<<<(256 * 512 + 255) / 256, 256, 0, stream>>>(T1, 1024, W3, 512, nullptr, Wcomb, 256, 512, 1024);
    naive_ab<<<(512 + 255) / 256, 256, 0, stream>>>(tb1, 1024, W3, 512, b3, bcomb, 1, 512, 1024);
    transpose_k<<<(256 * 512 + 255) / 256, 256, 0, stream>>>(Wcomb, 256, 512, WcombT);
    add_vec<<<4, 256, 0, stream>>>(bih0, bhh0, bias0, 1024);
    add_vec<<<4, 256, 0, stream>>>(bih1, bhh1, bias1, 1024);

    // ---- features ----
    feature_kernel<<<B_SZ / FB_SAMPLES, 256, 0, stream>>>(
        region_idx, poi_idx, car_idx, week_idx, time_idx, coords,
        region_tbl, poi_tbl, car_tbl, week_tbl, time_tbl,
        W_rp, b_rp, W_co, b_co, conv_w, conv_b, X);

    dim3 gemm_grid(1024 / BN, CHUNK / BM);

    // ---- both LSTM layers interleaved per timestep, 2 batch chunks ----
    for (int t = 0; t < T_CONV; t++) {
        for (int ch = 0; ch < 2; ch++) {
            size_t ro = (size_t)ch * CHUNK;  // row offset into batch

            // layer 0: gates = X_t @ Wih0^T + h0_{t-1} @ Whh0^T + bias0
            const float* A2a = (t == 0) ? nullptr : (h0 + ro * HID);
            gemm_dual<<<gemm_grid, 256, 0, stream>>>(
                X + ro * (8 * 59) + (size_t)t * 59, 8 * 59, 59, Wih0, 59,
                A2a, HID, HID, Whh0, HID,
                bias0, GT, 1024, CHUNK, 1024);
            lstm_pointwise<<<CHUNK, 256, 0, stream>>>(
                GT, 1024, c0 + ro * HID, h0 + ro * HID, HID, t == 0);

            // layer 1: gates = h0_t @ Wih1^T + h1_{t-1} @ Whh1^T + bias1
            const float* A2b = (t == 0) ? nullptr : (h1 + ro * HID);
            gemm_dual<<<gemm_grid, 256, 0, stream>>>(
                h0 + ro * HID, HID, HID, Wih1, HID,
                A2b, HID, HID, Whh1, HID,
                bias1, GT, 1024, CHUNK, 1024);
            lstm_pointwise<<<CHUNK, 256, 0, stream>>>(
                GT, 1024, c1 + ro * HID, h1 + ro * HID, HID, t == 0);
        }
    }

    // ---- collapsed head: out = h1 @ Wcomb + bcomb (overwrites GT scratch)
    dim3 fin_grid(512 / BN, B_SZ / BM);
    gemm_dual<<<fin_grid, 256, 0, stream>>>(
        h1, HID, HID, WcombT, HID,
        nullptr, 0, 0, nullptr, 0,
        bcomb, out, 512, B_SZ, 512);
}

// Round 4
// 1725.925 us; speedup vs baseline: 3.2933x; 3.2933x over previous
//
#include <hip/hip_runtime.h>
#include <hip/hip_bf16.h>
#include <math.h>

#define B_SZ 16384
#define T_CONV 8
#define HID 256

typedef __bf16 bf16x8 __attribute__((ext_vector_type(8)));
typedef float f32x4 __attribute__((ext_vector_type(4)));

__device__ __forceinline__ float fsigm(float x) { return 1.f / (1.f + __expf(-x)); }
__device__ __forceinline__ float ftanh(float x) {
    float t = __expf(-2.f * fabsf(x));
    float r = (1.f - t) / (1.f + t);
    return x >= 0.f ? r : -r;
}

// ---------------------------------------------------------------------------
// Feature kernel: embeddings -> nv -> conv(elu) -> Xp (B*8, 64) bf16, padded
// ---------------------------------------------------------------------------
#define FB_SAMPLES 4
__global__ __launch_bounds__(256) void feature_kernel(
    const int* __restrict__ region_idx, const int* __restrict__ poi_idx,
    const int* __restrict__ car_idx, const int* __restrict__ week_idx,
    const int* __restrict__ time_idx, const float* __restrict__ coords,
    const float* __restrict__ region_tbl, const float* __restrict__ poi_tbl,
    const float* __restrict__ car_tbl, const float* __restrict__ week_tbl,
    const float* __restrict__ time_tbl, const float* __restrict__ W_rp,
    const float* __restrict__ b_rp, const float* __restrict__ W_co,
    const float* __restrict__ b_co, const float* __restrict__ conv_w,
    const float* __restrict__ conv_b, __bf16* __restrict__ Xp)
{
    __shared__ float s_cw[3 * 40 * 32];
    __shared__ float s_nv[FB_SAMPLES][10][40];
    __shared__ float s_emb[FB_SAMPLES][27];
    __shared__ float s_rp[FB_SAMPLES][10][12];

    int tid = threadIdx.x;
    for (int i = tid; i < 3840; i += 256) s_cw[i] = conv_w[i];

    int s  = tid >> 6;
    int lt = tid & 63;
    int b  = blockIdx.x * FB_SAMPLES + s;

    if (lt < 27) {
        float v;
        if (lt < 16)      v = car_tbl[(size_t)car_idx[b] * 16 + lt];
        else if (lt < 19) v = week_tbl[week_idx[b] * 3 + (lt - 16)];
        else              v = time_tbl[time_idx[b] * 8 + (lt - 19)];
        s_emb[s][lt] = tanhf(v);
    }
    for (int i = lt; i < 120; i += 64) {
        int t = i / 12, k = i % 12;
        float v;
        if (k < 8) v = region_tbl[(size_t)region_idx[b * 10 + t] * 8 + k];
        else       v = poi_tbl[poi_idx[b * 10 + t] * 4 + (k - 8)];
        s_rp[s][t][k] = v;
    }
    __syncthreads();

    for (int i = lt; i < 400; i += 64) {
        int t = i / 40, j = i % 40;
        float acc;
        if (j < 32) {
            acc = b_rp[j];
            #pragma unroll
            for (int k = 0; k < 12; k++) acc += s_rp[s][t][k] * W_rp[k * 32 + j];
        } else {
            int j2 = j - 32;
            acc = b_co[j2] + coords[(size_t)(b * 10 + t) * 2 + 0] * W_co[j2]
                           + coords[(size_t)(b * 10 + t) * 2 + 1] * W_co[8 + j2];
        }
        s_nv[s][t][j] = acc;
    }
    __syncthreads();

    // conv (t=0..7, 32 outs) + elu -> Xp cols 0..31
    for (int i = lt; i < 256; i += 64) {
        int t = i >> 5, o = i & 31;
        float acc = conv_b[o];
        #pragma unroll
        for (int dt = 0; dt < 3; dt++)
            #pragma unroll
            for (int c = 0; c < 40; c++)
                acc += s_nv[s][t + dt][c] * s_cw[(dt * 40 + c) * 32 + o];
        acc = acc > 0.f ? acc : expm1f(acc);
        Xp[(size_t)(b * 8 + t) * 64 + o] = (__bf16)acc;
    }
    // emb broadcast -> cols 32..58
    for (int i = lt; i < 216; i += 64) {
        int t = i / 27, j = i % 27;
        Xp[(size_t)(b * 8 + t) * 64 + 32 + j] = (__bf16)s_emb[s][j];
    }
    // zero pad -> cols 59..63
    for (int i = lt; i < 40; i += 64) {
        int t = i / 5, j = i % 5;
        Xp[(size_t)(b * 8 + t) * 64 + 59 + j] = (__bf16)0.f;
    }
}

// ---------------------------------------------------------------------------
// Fused LSTM step (bf16 MFMA): gates = [A1|A2] @ W^T + bias, then pointwise.
// A1/A2: bf16 [M, lda] row-major (A2 region starts at k=K1, covered when
// kt*32 >= K1; at t0 pass KT so A2 is never touched). W: bf16 [1024, ldw].
// Block: 256 thr = 4 waves; tile M=128, N=64 per gate (x4 gates).
// Grid: (256/64, M/128) = (4, 128).
// ---------------------------------------------------------------------------
#define AST 40   // LDS row stride in bf16 (80B -> bank step 20, ~2-way)
__global__ __launch_bounds__(256) void lstm_fused(
    const __bf16* __restrict__ A1, int lda1, int K1,
    const __bf16* __restrict__ A2, int lda2,
    const __bf16* __restrict__ W, int ldw,
    const float* __restrict__ bias, float* __restrict__ cst,
    __bf16* __restrict__ hb, float* __restrict__ hf,
    int KT, int is_t0)
{
    __shared__ __align__(16) __bf16 As[128 * AST];      // 10 KB
    __shared__ __align__(16) __bf16 Bs[256 * AST];      // 20 KB

    int tid = threadIdx.x;
    int bm = blockIdx.y * 128;
    int bn = blockIdx.x * 64;           // gate-local col base (0..255)

    int l  = tid & 63;
    int wv = tid >> 6;
    int wm = wv * 32;
    int fr = l & 15;
    int fo = (l >> 4) * 8;

    f32x4 acc[2][4][4] = {};            // [mi][gate][nj]

    // staging coords
    int s_row  = tid >> 1;              // A: 128 rows, 2 thr/row
    int s_half = tid & 1;
    int s_g    = tid >> 6;              // B: 4 gates x 64 rows
    int s_r    = tid & 63;
    const __bf16* wrow = W + (size_t)(s_g * 256 + bn + s_r) * ldw;

    for (int kt = 0; kt < KT; kt++) {
        int k0 = kt * 32;
        // ---- stage A tile [128][32]
        {
            const __bf16* src;
            if (k0 < K1) src = A1 + (size_t)(bm + s_row) * lda1 + k0 + s_half * 16;
            else         src = A2 + (size_t)(bm + s_row) * lda2 + (k0 - K1) + s_half * 16;
            bf16x8 v0 = *(const bf16x8*)src;
            bf16x8 v1 = *(const bf16x8*)(src + 8);
            *(bf16x8*)&As[s_row * AST + s_half * 16]     = v0;
            *(bf16x8*)&As[s_row * AST + s_half * 16 + 8] = v1;
        }
        // ---- stage B tile [4][64][32]
        {
            const __bf16* src = wrow + k0;
            #pragma unroll
            for (int q = 0; q < 4; q++)
                *(bf16x8*)&Bs[(s_g * 64 + s_r) * AST + q * 8] = *(const bf16x8*)(src + q * 8);
        }
        __syncthreads();

        bf16x8 a0 = *(bf16x8*)&As[(wm + fr) * AST + fo];
        bf16x8 a1 = *(bf16x8*)&As[(wm + 16 + fr) * AST + fo];
        #pragma unroll
        for (int g = 0; g < 4; g++) {
            bf16x8 bfr[4];
            #pragma unroll
            for (int j = 0; j < 4; j++)
                bfr[j] = *(bf16x8*)&Bs[(g * 64 + j * 16 + fr) * AST + fo];
            #pragma unroll
            for (int j = 0; j < 4; j++) {
                acc[0][g][j] = __builtin_amdgcn_mfma_f32_16x16x32_bf16(a0, bfr[j], acc[0][g][j], 0, 0, 0);
                acc[1][g][j] = __builtin_amdgcn_mfma_f32_16x16x32_bf16(a1, bfr[j], acc[1][g][j], 0, 0, 0);
            }
        }
        __syncthreads();
    }

    // ---- epilogue: bias + LSTM pointwise (lane-local across the 4 gates)
    int rbase = (l >> 4) * 4;
    #pragma unroll
    for (int mi = 0; mi < 2; mi++) {
        #pragma unroll
        for (int j = 0; j < 4; j++) {
            int n = bn + j * 16 + fr;
            float bi = bias[n], bff = bias[256 + n], bg = bias[512 + n], bo = bias[768 + n];
            #pragma unroll
            for (int e = 0; e < 4; e++) {
                size_t m = (size_t)bm + wm + mi * 16 + rbase + e;
                size_t off = m * 256 + n;
                float gi = acc[mi][0][j][e] + bi;
                float gf = acc[mi][1][j][e] + bff;
                float gg = acc[mi][2][j][e] + bg;
                float go = acc[mi][3][j][e] + bo;
                float cold = is_t0 ? 0.f : cst[off];
                float cn = fsigm(gf) * cold + fsigm(gi) * ftanh(gg);
                float hn = fsigm(go) * ftanh(cn);
                cst[off] = cn;
                hb[off] = (__bf16)hn;
                if (hf) hf[off] = hn;
            }
        }
    }
}

// ---------------------------------------------------------------------------
// Tiled fp32 GEMM: C[M,N] = A[M,K] @ B[K,N] + bias. BM=BN=64, BK=16.
// 256 threads, 4x4 per thread. M,N % 64 == 0, K % 16 == 0.
// ---------------------------------------------------------------------------
__global__ __launch_bounds__(256) void gemm_nn(
    const float* __restrict__ A, int lda, const float* __restrict__ Bm, int ldb,
    const float* __restrict__ bias, float* __restrict__ C, int ldc,
    int M, int N, int K)
{
    __shared__ float As[16][68];
    __shared__ float Bs[16][68];
    int tid = threadIdx.x;
    int tx = tid & 15, ty = tid >> 4;
    int bm = blockIdx.y * 64, bn = blockIdx.x * 64;

    float acc[4][4] = {};

    for (int k0 = 0; k0 < K; k0 += 16) {
        for (int i = tid; i < 1024; i += 256) {
            int k = i & 15, m = i >> 4;
            As[k][m] = A[(size_t)(bm + m) * lda + k0 + k];
        }
        for (int i = tid; i < 1024; i += 256) {
            int n = i & 63, k = i >> 6;
            Bs[k][n] = Bm[(size_t)(k0 + k) * ldb + bn + n];
        }
        __syncthreads();
        #pragma unroll
        for (int kk = 0; kk < 16; kk++) {
            float4 a = *(const float4*)&As[kk][ty * 4];
            float4 b = *(const float4*)&Bs[kk][tx * 4];
            float av[4] = {a.x, a.y, a.z, a.w};
            float bv[4] = {b.x, b.y, b.z, b.w};
            #pragma unroll
            for (int i = 0; i < 4; i++)
                #pragma unroll
                for (int j = 0; j < 4; j++)
                    acc[i][j] += av[i] * bv[j];
        }
        __syncthreads();
    }

    #pragma unroll
    for (int i = 0; i < 4; i++) {
        int m = bm + ty * 4 + i;
        #pragma unroll
        for (int j = 0; j < 4; j++) {
            int n = bn + tx * 4 + j;
            C[(size_t)m * ldc + n] = acc[i][j] + (bias ? bias[n] : 0.f);
        }
    }
}

// ---------------------------------------------------------------------------
// Small helpers
// ---------------------------------------------------------------------------
__global__ void naive_ab(const float* __restrict__ A, int lda,
                         const float* __restrict__ Bm, int ldb,
                         const float* __restrict__ bias, float* __restrict__ C,
                         int M, int N, int K)
{
    int idx = blockIdx.x * 256 + threadIdx.x;
    if (idx >= M * N) return;
    int m = idx / N, n = idx % N;
    float acc = bias ? bias[n] : 0.f;
    for (int k = 0; k < K; k++) acc += A[(size_t)m * lda + k] * Bm[(size_t)k * ldb + n];
    C[idx] = acc;
}

__global__ void add_vec(const float* __restrict__ a, const float* __restrict__ b,
                        float* __restrict__ c, int n)
{
    int i = blockIdx.x * 256 + threadIdx.x;
    if (i < n) c[i] = a[i] + b[i];
}

// pack Wc0 [1024][320] bf16 = [Wih0 (59, pad to 64) | Whh0 (256)]
__global__ void pack_w0(const float* __restrict__ Wih, const float* __restrict__ Whh,
                        __bf16* __restrict__ Wc)
{
    int idx = blockIdx.x * 256 + threadIdx.x;
    if (idx >= 1024 * 320) return;
    int n = idx / 320, k = idx % 320;
    float v = (k < 59) ? Wih[(size_t)n * 59 + k]
            : (k < 64) ? 0.f
                       : Whh[(size_t)n * 256 + (k - 64)];
    Wc[idx] = (__bf16)v;
}

// pack Wc1 [1024][512] bf16 = [Wih1 (256) | Whh1 (256)]
__global__ void pack_w1(const float* __restrict__ Wih, const float* __restrict__ Whh,
                        __bf16* __restrict__ Wc)
{
    int idx = blockIdx.x * 256 + threadIdx.x;
    if (idx >= 1024 * 512) return;
    int n = idx / 512, k = idx % 512;
    float v = (k < 256) ? Wih[(size_t)n * 256 + k] : Whh[(size_t)n * 256 + (k - 256)];
    Wc[idx] = (__bf16)v;
}

// ---------------------------------------------------------------------------
extern "C" void kernel_launch(void* const* d_in, const int* in_sizes, int n_in,
                              void* d_out, int out_size, void* d_ws, size_t ws_size,
                              hipStream_t stream)
{
    const int*   region_idx = (const int*)d_in[0];
    const int*   poi_idx    = (const int*)d_in[1];
    const int*   car_idx    = (const int*)d_in[2];
    const int*   week_idx   = (const int*)d_in[3];
    const int*   time_idx   = (const int*)d_in[4];
    const float* coords     = (const float*)d_in[5];
    const float* region_tbl = (const float*)d_in[6];
    const float* poi_tbl    = (const float*)d_in[7];
    const float* car_tbl    = (const float*)d_in[8];
    const float* week_tbl   = (const float*)d_in[9];
    const float* time_tbl   = (const float*)d_in[10];
    const float* W_rp   = (const float*)d_in[11];
    const float* b_rp   = (const float*)d_in[12];
    const float* W_co   = (const float*)d_in[13];
    const float* b_co   = (const float*)d_in[14];
    const float* conv_w = (const float*)d_in[15];
    const float* conv_b = (const float*)d_in[16];
    const float* Wih0 = (const float*)d_in[17];
    const float* Whh0 = (const float*)d_in[18];
    const float* bih0 = (const float*)d_in[19];
    const float* bhh0 = (const float*)d_in[20];
    const float* Wih1 = (const float*)d_in[21];
    const float* Whh1 = (const float*)d_in[22];
    const float* bih1 = (const float*)d_in[23];
    const float* bhh1 = (const float*)d_in[24];
    const float* W1 = (const float*)d_in[25];
    const float* b1 = (const float*)d_in[26];
    const float* W2 = (const float*)d_in[27];
    const float* b2 = (const float*)d_in[28];
    const float* W3 = (const float*)d_in[29];
    const float* b3 = (const float*)d_in[30];
    float* out = (float*)d_out;

    // ---- workspace layout (~88 MB) ----
    char* ws = (char*)d_ws;
    size_t off = 0;
    auto alloc = [&](size_t bytes) -> char* {
        char* p = ws + off;
        off = (off + bytes + 255) & ~(size_t)255;
        return p;
    };
    __bf16* Xp   = (__bf16*)alloc((size_t)B_SZ * 8 * 64 * 2);   // 16.8 MB
    __bf16* h0b  = (__bf16*)alloc((size_t)B_SZ * HID * 2);      // 8.4 MB
    __bf16* h1b  = (__bf16*)alloc((size_t)B_SZ * HID * 2);      // 8.4 MB
    float*  c0   = (float*)alloc((size_t)B_SZ * HID * 4);       // 16.8 MB
    float*  c1   = (float*)alloc((size_t)B_SZ * HID * 4);       // 16.8 MB
    float*  h1f  = (float*)alloc((size_t)B_SZ * HID * 4);       // 16.8 MB
    __bf16* Wc0  = (__bf16*)alloc(1024 * 320 * 2);
    __bf16* Wc1  = (__bf16*)alloc(1024 * 512 * 2);
    float*  T1    = (float*)alloc(256 * 1024 * 4);
    float*  tb1   = (float*)alloc(1024 * 4);
    float*  Wcomb = (float*)alloc(256 * 512 * 4);
    float*  bcomb = (float*)alloc(512 * 4);
    float*  bias0 = (float*)alloc(1024 * 4);
    float*  bias1 = (float*)alloc(1024 * 4);
    (void)ws_size;

    // ---- weight prep ----
    pack_w0<<<(1024 * 320 + 255) / 256, 256, 0, stream>>>(Wih0, Whh0, Wc0);
    pack_w1<<<(1024 * 512 + 255) / 256, 256, 0, stream>>>(Wih1, Whh1, Wc1);
    add_vec<<<4, 256, 0, stream>>>(bih0, bhh0, bias0, 1024);
    add_vec<<<4, 256, 0, stream>>>(bih1, bhh1, bias1, 1024);

    // ---- collapse head: Wcomb = W1@W2@W3, bcomb = (b1@W2+b2)@W3+b3 ----
    gemm_nn<<<dim3(16, 4), 256, 0, stream>>>(W1, 512, W2, 1024, nullptr, T1, 1024, 256, 1024, 512);
    naive_ab<<<4, 256, 0, stream>>>(b1, 512, W2, 1024, b2, tb1, 1, 1024, 512);
    gemm_nn<<<dim3(8, 4), 256, 0, stream>>>(T1, 1024, W3, 512, nullptr, Wcomb, 512, 256, 512, 1024);
    naive_ab<<<2, 256, 0, stream>>>(tb1, 1024, W3, 512, b3, bcomb, 1, 512, 1024);

    // ---- features -> Xp bf16 ----
    feature_kernel<<<B_SZ / FB_SAMPLES, 256, 0, stream>>>(
        region_idx, poi_idx, car_idx, week_idx, time_idx, coords,
        region_tbl, poi_tbl, car_tbl, week_tbl, time_tbl,
        W_rp, b_rp, W_co, b_co, conv_w, conv_b, Xp);

    // ---- LSTM: both layers interleaved per timestep, full batch ----
    dim3 lstm_grid(4, B_SZ / 128);
    for (int t = 0; t < T_CONV; t++) {
        // layer 0: A = [Xp_t (64) | h0_prev (256)], W = Wc0 [1024][320]
        lstm_fused<<<lstm_grid, 256, 0, stream>>>(
            Xp + (size_t)t * 64, 8 * 64, 64,
            h0b, HID,
            Wc0, 320, bias0, c0, h0b, nullptr,
            t == 0 ? 2 : 10, t == 0);

        // layer 1: A = [h0_t (256) | h1_prev (256)], W = Wc1 [1024][512]
        lstm_fused<<<lstm_grid, 256, 0, stream>>>(
            h0b, HID, 256,
            h1b, HID,
            Wc1, 512, bias1, c1, h1b, (t == T_CONV - 1) ? h1f : nullptr,
            t == 0 ? 8 : 16, t == 0);
    }

    // ---- collapsed head: out = h1f @ Wcomb + bcomb (fp32) ----
    gemm_nn<<<dim3(512 / 64, B_SZ / 64), 256, 0, stream>>>(
        h1f, HID, Wcomb, 512, bcomb, out, 512, B_SZ, 512, HID);
}

// Round 5
// 1382.890 us; speedup vs baseline: 4.1102x; 1.2481x over previous
//
#include <hip/hip_runtime.h>
#include <hip/hip_bf16.h>
#include <math.h>

#define B_SZ 16384
#define T_CONV 8
#define HID 256

typedef __bf16 bf16x8 __attribute__((ext_vector_type(8)));
typedef float f32x4 __attribute__((ext_vector_type(4)));

__device__ __forceinline__ float fsigm(float x) { return 1.f / (1.f + __expf(-x)); }
__device__ __forceinline__ float ftanh(float x) {
    float t = __expf(-2.f * fabsf(x));
    float r = (1.f - t) / (1.f + t);
    return x >= 0.f ? r : -r;
}

// ---------------------------------------------------------------------------
// Feature kernel: embeddings -> nv -> conv(elu) -> Xp (B*8, 64) bf16, padded
// ---------------------------------------------------------------------------
#define FB_SAMPLES 4
__global__ __launch_bounds__(256) void feature_kernel(
    const int* __restrict__ region_idx, const int* __restrict__ poi_idx,
    const int* __restrict__ car_idx, const int* __restrict__ week_idx,
    const int* __restrict__ time_idx, const float* __restrict__ coords,
    const float* __restrict__ region_tbl, const float* __restrict__ poi_tbl,
    const float* __restrict__ car_tbl, const float* __restrict__ week_tbl,
    const float* __restrict__ time_tbl, const float* __restrict__ W_rp,
    const float* __restrict__ b_rp, const float* __restrict__ W_co,
    const float* __restrict__ b_co, const float* __restrict__ conv_w,
    const float* __restrict__ conv_b, __bf16* __restrict__ Xp)
{
    __shared__ float s_cw[3 * 40 * 32];
    __shared__ float s_nv[FB_SAMPLES][10][40];
    __shared__ float s_emb[FB_SAMPLES][27];
    __shared__ float s_rp[FB_SAMPLES][10][12];

    int tid = threadIdx.x;
    for (int i = tid; i < 3840; i += 256) s_cw[i] = conv_w[i];

    int s  = tid >> 6;
    int lt = tid & 63;
    int b  = blockIdx.x * FB_SAMPLES + s;

    if (lt < 27) {
        float v;
        if (lt < 16)      v = car_tbl[(size_t)car_idx[b] * 16 + lt];
        else if (lt < 19) v = week_tbl[week_idx[b] * 3 + (lt - 16)];
        else              v = time_tbl[time_idx[b] * 8 + (lt - 19)];
        s_emb[s][lt] = tanhf(v);
    }
    for (int i = lt; i < 120; i += 64) {
        int t = i / 12, k = i % 12;
        float v;
        if (k < 8) v = region_tbl[(size_t)region_idx[b * 10 + t] * 8 + k];
        else       v = poi_tbl[poi_idx[b * 10 + t] * 4 + (k - 8)];
        s_rp[s][t][k] = v;
    }
    __syncthreads();

    for (int i = lt; i < 400; i += 64) {
        int t = i / 40, j = i % 40;
        float acc;
        if (j < 32) {
            acc = b_rp[j];
            #pragma unroll
            for (int k = 0; k < 12; k++) acc += s_rp[s][t][k] * W_rp[k * 32 + j];
        } else {
            int j2 = j - 32;
            acc = b_co[j2] + coords[(size_t)(b * 10 + t) * 2 + 0] * W_co[j2]
                           + coords[(size_t)(b * 10 + t) * 2 + 1] * W_co[8 + j2];
        }
        s_nv[s][t][j] = acc;
    }
    __syncthreads();

    // conv (t=0..7, 32 outs) + elu -> Xp cols 0..31
    for (int i = lt; i < 256; i += 64) {
        int t = i >> 5, o = i & 31;
        float acc = conv_b[o];
        #pragma unroll
        for (int dt = 0; dt < 3; dt++)
            #pragma unroll
            for (int c = 0; c < 40; c++)
                acc += s_nv[s][t + dt][c] * s_cw[(dt * 40 + c) * 32 + o];
        acc = acc > 0.f ? acc : expm1f(acc);
        Xp[(size_t)(b * 8 + t) * 64 + o] = (__bf16)acc;
    }
    // emb broadcast -> cols 32..58
    for (int i = lt; i < 216; i += 64) {
        int t = i / 27, j = i % 27;
        Xp[(size_t)(b * 8 + t) * 64 + 32 + j] = (__bf16)s_emb[s][j];
    }
    // zero pad -> cols 59..63
    for (int i = lt; i < 40; i += 64) {
        int t = i / 5, j = i % 5;
        Xp[(size_t)(b * 8 + t) * 64 + 59 + j] = (__bf16)0.f;
    }
}

// ---------------------------------------------------------------------------
// Fused LSTM step (bf16 MFMA): gates = [A1|A2] @ W^T + bias, then pointwise.
// ---------------------------------------------------------------------------
#define AST 40   // LDS row stride in bf16 (80B -> bank step 20, ~2-way)
__global__ __launch_bounds__(256) void lstm_fused(
    const __bf16* __restrict__ A1, int lda1, int K1,
    const __bf16* __restrict__ A2, int lda2,
    const __bf16* __restrict__ W, int ldw,
    const float* __restrict__ bias, float* __restrict__ cst,
    __bf16* __restrict__ hb, float* __restrict__ hf,
    int KT, int is_t0)
{
    __shared__ __align__(16) __bf16 As[128 * AST];      // 10 KB
    __shared__ __align__(16) __bf16 Bs[256 * AST];      // 20 KB

    int tid = threadIdx.x;
    int bm = blockIdx.y * 128;
    int bn = blockIdx.x * 64;           // gate-local col base (0..255)

    int l  = tid & 63;
    int wv = tid >> 6;
    int wm = wv * 32;
    int fr = l & 15;
    int fo = (l >> 4) * 8;

    f32x4 acc[2][4][4] = {};            // [mi][gate][nj]

    // staging coords
    int s_row  = tid >> 1;              // A: 128 rows, 2 thr/row
    int s_half = tid & 1;
    int s_g    = tid >> 6;              // B: 4 gates x 64 rows
    int s_r    = tid & 63;
    const __bf16* wrow = W + (size_t)(s_g * 256 + bn + s_r) * ldw;

    for (int kt = 0; kt < KT; kt++) {
        int k0 = kt * 32;
        // ---- stage A tile [128][32]
        {
            const __bf16* src;
            if (k0 < K1) src = A1 + (size_t)(bm + s_row) * lda1 + k0 + s_half * 16;
            else         src = A2 + (size_t)(bm + s_row) * lda2 + (k0 - K1) + s_half * 16;
            bf16x8 v0 = *(const bf16x8*)src;
            bf16x8 v1 = *(const bf16x8*)(src + 8);
            *(bf16x8*)&As[s_row * AST + s_half * 16]     = v0;
            *(bf16x8*)&As[s_row * AST + s_half * 16 + 8] = v1;
        }
        // ---- stage B tile [4][64][32]
        {
            const __bf16* src = wrow + k0;
            #pragma unroll
            for (int q = 0; q < 4; q++)
                *(bf16x8*)&Bs[(s_g * 64 + s_r) * AST + q * 8] = *(const bf16x8*)(src + q * 8);
        }
        __syncthreads();

        bf16x8 a0 = *(bf16x8*)&As[(wm + fr) * AST + fo];
        bf16x8 a1 = *(bf16x8*)&As[(wm + 16 + fr) * AST + fo];
        #pragma unroll
        for (int g = 0; g < 4; g++) {
            bf16x8 bfr[4];
            #pragma unroll
            for (int j = 0; j < 4; j++)
                bfr[j] = *(bf16x8*)&Bs[(g * 64 + j * 16 + fr) * AST + fo];
            #pragma unroll
            for (int j = 0; j < 4; j++) {
                acc[0][g][j] = __builtin_amdgcn_mfma_f32_16x16x32_bf16(a0, bfr[j], acc[0][g][j], 0, 0, 0);
                acc[1][g][j] = __builtin_amdgcn_mfma_f32_16x16x32_bf16(a1, bfr[j], acc[1][g][j], 0, 0, 0);
            }
        }
        __syncthreads();
    }

    // ---- epilogue: bias + LSTM pointwise (lane-local across the 4 gates)
    int rbase = (l >> 4) * 4;
    #pragma unroll
    for (int mi = 0; mi < 2; mi++) {
        #pragma unroll
        for (int j = 0; j < 4; j++) {
            int n = bn + j * 16 + fr;
            float bi = bias[n], bff = bias[256 + n], bg = bias[512 + n], bo = bias[768 + n];
            #pragma unroll
            for (int e = 0; e < 4; e++) {
                size_t m = (size_t)bm + wm + mi * 16 + rbase + e;
                size_t off = m * 256 + n;
                float gi = acc[mi][0][j][e] + bi;
                float gf = acc[mi][1][j][e] + bff;
                float gg = acc[mi][2][j][e] + bg;
                float go = acc[mi][3][j][e] + bo;
                float cold = is_t0 ? 0.f : cst[off];
                float cn = fsigm(gf) * cold + fsigm(gi) * ftanh(gg);
                float hn = fsigm(go) * ftanh(cn);
                cst[off] = cn;
                hb[off] = (__bf16)hn;
                if (hf) hf[off] = hn;
            }
        }
    }
}

// ---------------------------------------------------------------------------
// Tiled fp32 GEMM: C[M,N] = A[M,K] @ B[K,N] + bias. BM=BN=64, BK=16.
// ---------------------------------------------------------------------------
__global__ __launch_bounds__(256) void gemm_nn(
    const float* __restrict__ A, int lda, const float* __restrict__ Bm, int ldb,
    const float* __restrict__ bias, float* __restrict__ C, int ldc,
    int M, int N, int K)
{
    __shared__ float As[16][68];
    __shared__ float Bs[16][68];
    int tid = threadIdx.x;
    int tx = tid & 15, ty = tid >> 4;
    int bm = blockIdx.y * 64, bn = blockIdx.x * 64;

    float acc[4][4] = {};

    for (int k0 = 0; k0 < K; k0 += 16) {
        for (int i = tid; i < 1024; i += 256) {
            int k = i & 15, m = i >> 4;
            As[k][m] = A[(size_t)(bm + m) * lda + k0 + k];
        }
        for (int i = tid; i < 1024; i += 256) {
            int n = i & 63, k = i >> 6;
            Bs[k][n] = Bm[(size_t)(k0 + k) * ldb + bn + n];
        }
        __syncthreads();
        #pragma unroll
        for (int kk = 0; kk < 16; kk++) {
            float4 a = *(const float4*)&As[kk][ty * 4];
            float4 b = *(const float4*)&Bs[kk][tx * 4];
            float av[4] = {a.x, a.y, a.z, a.w};
            float bv[4] = {b.x, b.y, b.z, b.w};
            #pragma unroll
            for (int i = 0; i < 4; i++)
                #pragma unroll
                for (int j = 0; j < 4; j++)
                    acc[i][j] += av[i] * bv[j];
        }
        __syncthreads();
    }

    #pragma unroll
    for (int i = 0; i < 4; i++) {
        int m = bm + ty * 4 + i;
        #pragma unroll
        for (int j = 0; j < 4; j++) {
            int n = bn + tx * 4 + j;
            C[(size_t)m * ldc + n] = acc[i][j] + (bias ? bias[n] : 0.f);
        }
    }
}

// ---------------------------------------------------------------------------
// vecmat: outv[n] = bias[n] + sum_k v[k] * M[k*ldb + n]
// 64 outputs per block (1/lane, coalesced), 4 waves split K, 8-way ILP.
// Requires K % 32 == 0, N % 64 == 0.
// ---------------------------------------------------------------------------
__global__ __launch_bounds__(256) void vecmat(
    const float* __restrict__ v, const float* __restrict__ M, int ldb, int K,
    const float* __restrict__ bias, float* __restrict__ outv)
{
    __shared__ float red[4][64];
    int l = threadIdx.x & 63;
    int w = threadIdx.x >> 6;
    int n = blockIdx.x * 64 + l;
    int kpw = K >> 2;
    int k0 = w * kpw;

    float p[8] = {};
    for (int k = k0; k < k0 + kpw; k += 8) {
        #pragma unroll
        for (int u = 0; u < 8; u++)
            p[u] += v[k + u] * M[(size_t)(k + u) * ldb + n];
    }
    red[w][l] = ((p[0] + p[1]) + (p[2] + p[3])) + ((p[4] + p[5]) + (p[6] + p[7]));
    __syncthreads();
    if (w == 0)
        outv[n] = red[0][l] + red[1][l] + red[2][l] + red[3][l]
                + (bias ? bias[n] : 0.f);
}

// ---------------------------------------------------------------------------
// Small helpers
// ---------------------------------------------------------------------------
__global__ void add_vec(const float* __restrict__ a, const float* __restrict__ b,
                        float* __restrict__ c, int n)
{
    int i = blockIdx.x * 256 + threadIdx.x;
    if (i < n) c[i] = a[i] + b[i];
}

// pack Wc0 [1024][320] bf16 = [Wih0 (59, pad to 64) | Whh0 (256)]
__global__ void pack_w0(const float* __restrict__ Wih, const float* __restrict__ Whh,
                        __bf16* __restrict__ Wc)
{
    int idx = blockIdx.x * 256 + threadIdx.x;
    if (idx >= 1024 * 320) return;
    int n = idx / 320, k = idx % 320;
    float v = (k < 59) ? Wih[(size_t)n * 59 + k]
            : (k < 64) ? 0.f
                       : Whh[(size_t)n * 256 + (k - 64)];
    Wc[idx] = (__bf16)v;
}

// pack Wc1 [1024][512] bf16 = [Wih1 (256) | Whh1 (256)]
__global__ void pack_w1(const float* __restrict__ Wih, const float* __restrict__ Whh,
                        __bf16* __restrict__ Wc)
{
    int idx = blockIdx.x * 256 + threadIdx.x;
    if (idx >= 1024 * 512) return;
    int n = idx / 512, k = idx % 512;
    float v = (k < 256) ? Wih[(size_t)n * 256 + k] : Whh[(size_t)n * 256 + (k - 256)];
    Wc[idx] = (__bf16)v;
}

// ---------------------------------------------------------------------------
extern "C" void kernel_launch(void* const* d_in, const int* in_sizes, int n_in,
                              void* d_out, int out_size, void* d_ws, size_t ws_size,
                              hipStream_t stream)
{
    const int*   region_idx = (const int*)d_in[0];
    const int*   poi_idx    = (const int*)d_in[1];
    const int*   car_idx    = (const int*)d_in[2];
    const int*   week_idx   = (const int*)d_in[3];
    const int*   time_idx   = (const int*)d_in[4];
    const float* coords     = (const float*)d_in[5];
    const float* region_tbl = (const float*)d_in[6];
    const float* poi_tbl    = (const float*)d_in[7];
    const float* car_tbl    = (const float*)d_in[8];
    const float* week_tbl   = (const float*)d_in[9];
    const float* time_tbl   = (const float*)d_in[10];
    const float* W_rp   = (const float*)d_in[11];
    const float* b_rp   = (const float*)d_in[12];
    const float* W_co   = (const float*)d_in[13];
    const float* b_co   = (const float*)d_in[14];
    const float* conv_w = (const float*)d_in[15];
    const float* conv_b = (const float*)d_in[16];
    const float* Wih0 = (const float*)d_in[17];
    const float* Whh0 = (const float*)d_in[18];
    const float* bih0 = (const float*)d_in[19];
    const float* bhh0 = (const float*)d_in[20];
    const float* Wih1 = (const float*)d_in[21];
    const float* Whh1 = (const float*)d_in[22];
    const float* bih1 = (const float*)d_in[23];
    const float* bhh1 = (const float*)d_in[24];
    const float* W1 = (const float*)d_in[25];
    const float* b1 = (const float*)d_in[26];
    const float* W2 = (const float*)d_in[27];
    const float* b2 = (const float*)d_in[28];
    const float* W3 = (const float*)d_in[29];
    const float* b3 = (const float*)d_in[30];
    float* out = (float*)d_out;

    // ---- workspace layout (~88 MB) ----
    char* ws = (char*)d_ws;
    size_t off = 0;
    auto alloc = [&](size_t bytes) -> char* {
        char* p = ws + off;
        off = (off + bytes + 255) & ~(size_t)255;
        return p;
    };
    __bf16* Xp   = (__bf16*)alloc((size_t)B_SZ * 8 * 64 * 2);   // 16.8 MB
    __bf16* h0b  = (__bf16*)alloc((size_t)B_SZ * HID * 2);      // 8.4 MB
    __bf16* h1b  = (__bf16*)alloc((size_t)B_SZ * HID * 2);      // 8.4 MB
    float*  c0   = (float*)alloc((size_t)B_SZ * HID * 4);       // 16.8 MB
    float*  c1   = (float*)alloc((size_t)B_SZ * HID * 4);       // 16.8 MB
    float*  h1f  = (float*)alloc((size_t)B_SZ * HID * 4);       // 16.8 MB
    __bf16* Wc0  = (__bf16*)alloc(1024 * 320 * 2);
    __bf16* Wc1  = (__bf16*)alloc(1024 * 512 * 2);
    float*  T1    = (float*)alloc(256 * 1024 * 4);
    float*  tb1   = (float*)alloc(1024 * 4);
    float*  Wcomb = (float*)alloc(256 * 512 * 4);
    float*  bcomb = (float*)alloc(512 * 4);
    float*  bias0 = (float*)alloc(1024 * 4);
    float*  bias1 = (float*)alloc(1024 * 4);
    (void)ws_size;

    // ---- weight prep ----
    pack_w0<<<(1024 * 320 + 255) / 256, 256, 0, stream>>>(Wih0, Whh0, Wc0);
    pack_w1<<<(1024 * 512 + 255) / 256, 256, 0, stream>>>(Wih1, Whh1, Wc1);
    add_vec<<<4, 256, 0, stream>>>(bih0, bhh0, bias0, 1024);
    add_vec<<<4, 256, 0, stream>>>(bih1, bhh1, bias1, 1024);

    // ---- collapse head: Wcomb = W1@W2@W3, bcomb = (b1@W2+b2)@W3+b3 ----
    gemm_nn<<<dim3(16, 4), 256, 0, stream>>>(W1, 512, W2, 1024, nullptr, T1, 1024, 256, 1024, 512);
    vecmat<<<16, 256, 0, stream>>>(b1, W2, 1024, 512, b2, tb1);
    gemm_nn<<<dim3(8, 4), 256, 0, stream>>>(T1, 1024, W3, 512, nullptr, Wcomb, 512, 256, 512, 1024);
    vecmat<<<8, 256, 0, stream>>>(tb1, W3, 512, 1024, b3, bcomb);

    // ---- features -> Xp bf16 ----
    feature_kernel<<<B_SZ / FB_SAMPLES, 256, 0, stream>>>(
        region_idx, poi_idx, car_idx, week_idx, time_idx, coords,
        region_tbl, poi_tbl, car_tbl, week_tbl, time_tbl,
        W_rp, b_rp, W_co, b_co, conv_w, conv_b, Xp);

    // ---- LSTM: both layers interleaved per timestep, full batch ----
    dim3 lstm_grid(4, B_SZ / 128);
    for (int t = 0; t < T_CONV; t++) {
        // layer 0: A = [Xp_t (64) | h0_prev (256)], W = Wc0 [1024][320]
        lstm_fused<<<lstm_grid, 256, 0, stream>>>(
            Xp + (size_t)t * 64, 8 * 64, 64,
            h0b, HID,
            Wc0, 320, bias0, c0, h0b, nullptr,
            t == 0 ? 2 : 10, t == 0);

        // layer 1: A = [h0_t (256) | h1_prev (256)], W = Wc1 [1024][512]
        lstm_fused<<<lstm_grid, 256, 0, stream>>>(
            h0b, HID, 256,
            h1b, HID,
            Wc1, 512, bias1, c1, h1b, (t == T_CONV - 1) ? h1f : nullptr,
            t == 0 ? 8 : 16, t == 0);
    }

    // ---- collapsed head: out = h1f @ Wcomb + bcomb (fp32) ----
    gemm_nn<<<dim3(512 / 64, B_SZ / 64), 256, 0, stream>>>(
        h1f, HID, Wcomb, 512, bcomb, out, 512, B_SZ, 512, HID);
}

// Round 6
// 1192.037 us; speedup vs baseline: 4.7683x; 1.1601x over previous
//
#include <hip/hip_runtime.h>
#include <hip/hip_bf16.h>
#include <math.h>

#define B_SZ 16384
#define T_CONV 8
#define HID 256
#define SK 16   // split-K slices for the weight-collapse GEMMs

typedef __bf16 bf16x8 __attribute__((ext_vector_type(8)));
typedef float f32x4 __attribute__((ext_vector_type(4)));

__device__ __forceinline__ float fsigm(float x) { return 1.f / (1.f + __expf(-x)); }
__device__ __forceinline__ float ftanh(float x) {
    float t = __expf(-2.f * fabsf(x));
    float r = (1.f - t) / (1.f + t);
    return x >= 0.f ? r : -r;
}

// ---------------------------------------------------------------------------
// Feature kernel: embeddings -> nv -> conv(elu) -> Xp (B*8, 64) bf16, padded
// ---------------------------------------------------------------------------
#define FB_SAMPLES 4
__global__ __launch_bounds__(256) void feature_kernel(
    const int* __restrict__ region_idx, const int* __restrict__ poi_idx,
    const int* __restrict__ car_idx, const int* __restrict__ week_idx,
    const int* __restrict__ time_idx, const float* __restrict__ coords,
    const float* __restrict__ region_tbl, const float* __restrict__ poi_tbl,
    const float* __restrict__ car_tbl, const float* __restrict__ week_tbl,
    const float* __restrict__ time_tbl, const float* __restrict__ W_rp,
    const float* __restrict__ b_rp, const float* __restrict__ W_co,
    const float* __restrict__ b_co, const float* __restrict__ conv_w,
    const float* __restrict__ conv_b, __bf16* __restrict__ Xp)
{
    __shared__ float s_cw[3 * 40 * 32];
    __shared__ float s_nv[FB_SAMPLES][10][40];
    __shared__ float s_emb[FB_SAMPLES][27];
    __shared__ float s_rp[FB_SAMPLES][10][12];

    int tid = threadIdx.x;
    for (int i = tid; i < 3840; i += 256) s_cw[i] = conv_w[i];

    int s  = tid >> 6;
    int lt = tid & 63;
    int b  = blockIdx.x * FB_SAMPLES + s;

    if (lt < 27) {
        float v;
        if (lt < 16)      v = car_tbl[(size_t)car_idx[b] * 16 + lt];
        else if (lt < 19) v = week_tbl[week_idx[b] * 3 + (lt - 16)];
        else              v = time_tbl[time_idx[b] * 8 + (lt - 19)];
        s_emb[s][lt] = tanhf(v);
    }
    for (int i = lt; i < 120; i += 64) {
        int t = i / 12, k = i % 12;
        float v;
        if (k < 8) v = region_tbl[(size_t)region_idx[b * 10 + t] * 8 + k];
        else       v = poi_tbl[poi_idx[b * 10 + t] * 4 + (k - 8)];
        s_rp[s][t][k] = v;
    }
    __syncthreads();

    for (int i = lt; i < 400; i += 64) {
        int t = i / 40, j = i % 40;
        float acc;
        if (j < 32) {
            acc = b_rp[j];
            #pragma unroll
            for (int k = 0; k < 12; k++) acc += s_rp[s][t][k] * W_rp[k * 32 + j];
        } else {
            int j2 = j - 32;
            acc = b_co[j2] + coords[(size_t)(b * 10 + t) * 2 + 0] * W_co[j2]
                           + coords[(size_t)(b * 10 + t) * 2 + 1] * W_co[8 + j2];
        }
        s_nv[s][t][j] = acc;
    }
    __syncthreads();

    // conv (t=0..7, 32 outs) + elu -> Xp cols 0..31
    for (int i = lt; i < 256; i += 64) {
        int t = i >> 5, o = i & 31;
        float acc = conv_b[o];
        #pragma unroll
        for (int dt = 0; dt < 3; dt++)
            #pragma unroll
            for (int c = 0; c < 40; c++)
                acc += s_nv[s][t + dt][c] * s_cw[(dt * 40 + c) * 32 + o];
        acc = acc > 0.f ? acc : expm1f(acc);
        Xp[(size_t)(b * 8 + t) * 64 + o] = (__bf16)acc;
    }
    // emb broadcast -> cols 32..58
    for (int i = lt; i < 216; i += 64) {
        int t = i / 27, j = i % 27;
        Xp[(size_t)(b * 8 + t) * 64 + 32 + j] = (__bf16)s_emb[s][j];
    }
    // zero pad -> cols 59..63
    for (int i = lt; i < 40; i += 64) {
        int t = i / 5, j = i % 5;
        Xp[(size_t)(b * 8 + t) * 64 + 59 + j] = (__bf16)0.f;
    }
}

// ---------------------------------------------------------------------------
// Fused LSTM step (bf16 MFMA): gates = [A1|A2] @ W^T + bias, then pointwise.
// ---------------------------------------------------------------------------
#define AST 40   // LDS row stride in bf16 (80B -> bank step 20, ~2-way)
__global__ __launch_bounds__(256) void lstm_fused(
    const __bf16* __restrict__ A1, int lda1, int K1,
    const __bf16* __restrict__ A2, int lda2,
    const __bf16* __restrict__ W, int ldw,
    const float* __restrict__ bias, float* __restrict__ cst,
    __bf16* __restrict__ hb, float* __restrict__ hf,
    int KT, int is_t0)
{
    __shared__ __align__(16) __bf16 As[128 * AST];      // 10 KB
    __shared__ __align__(16) __bf16 Bs[256 * AST];      // 20 KB

    int tid = threadIdx.x;
    int bm = blockIdx.y * 128;
    int bn = blockIdx.x * 64;           // gate-local col base (0..255)

    int l  = tid & 63;
    int wv = tid >> 6;
    int wm = wv * 32;
    int fr = l & 15;
    int fo = (l >> 4) * 8;

    f32x4 acc[2][4][4] = {};            // [mi][gate][nj]

    // staging coords
    int s_row  = tid >> 1;              // A: 128 rows, 2 thr/row
    int s_half = tid & 1;
    int s_g    = tid >> 6;              // B: 4 gates x 64 rows
    int s_r    = tid & 63;
    const __bf16* wrow = W + (size_t)(s_g * 256 + bn + s_r) * ldw;

    for (int kt = 0; kt < KT; kt++) {
        int k0 = kt * 32;
        // ---- stage A tile [128][32]
        {
            const __bf16* src;
            if (k0 < K1) src = A1 + (size_t)(bm + s_row) * lda1 + k0 + s_half * 16;
            else         src = A2 + (size_t)(bm + s_row) * lda2 + (k0 - K1) + s_half * 16;
            bf16x8 v0 = *(const bf16x8*)src;
            bf16x8 v1 = *(const bf16x8*)(src + 8);
            *(bf16x8*)&As[s_row * AST + s_half * 16]     = v0;
            *(bf16x8*)&As[s_row * AST + s_half * 16 + 8] = v1;
        }
        // ---- stage B tile [4][64][32]
        {
            const __bf16* src = wrow + k0;
            #pragma unroll
            for (int q = 0; q < 4; q++)
                *(bf16x8*)&Bs[(s_g * 64 + s_r) * AST + q * 8] = *(const bf16x8*)(src + q * 8);
        }
        __syncthreads();

        bf16x8 a0 = *(bf16x8*)&As[(wm + fr) * AST + fo];
        bf16x8 a1 = *(bf16x8*)&As[(wm + 16 + fr) * AST + fo];
        #pragma unroll
        for (int g = 0; g < 4; g++) {
            bf16x8 bfr[4];
            #pragma unroll
            for (int j = 0; j < 4; j++)
                bfr[j] = *(bf16x8*)&Bs[(g * 64 + j * 16 + fr) * AST + fo];
            #pragma unroll
            for (int j = 0; j < 4; j++) {
                acc[0][g][j] = __builtin_amdgcn_mfma_f32_16x16x32_bf16(a0, bfr[j], acc[0][g][j], 0, 0, 0);
                acc[1][g][j] = __builtin_amdgcn_mfma_f32_16x16x32_bf16(a1, bfr[j], acc[1][g][j], 0, 0, 0);
            }
        }
        __syncthreads();
    }

    // ---- epilogue: bias + LSTM pointwise (lane-local across the 4 gates)
    int rbase = (l >> 4) * 4;
    #pragma unroll
    for (int mi = 0; mi < 2; mi++) {
        #pragma unroll
        for (int j = 0; j < 4; j++) {
            int n = bn + j * 16 + fr;
            float bi = bias[n], bff = bias[256 + n], bg = bias[512 + n], bo = bias[768 + n];
            #pragma unroll
            for (int e = 0; e < 4; e++) {
                size_t m = (size_t)bm + wm + mi * 16 + rbase + e;
                size_t off = m * 256 + n;
                float gi = acc[mi][0][j][e] + bi;
                float gf = acc[mi][1][j][e] + bff;
                float gg = acc[mi][2][j][e] + bg;
                float go = acc[mi][3][j][e] + bo;
                float cold = is_t0 ? 0.f : cst[off];
                float cn = fsigm(gf) * cold + fsigm(gi) * ftanh(gg);
                float hn = fsigm(go) * ftanh(cn);
                cst[off] = cn;
                hb[off] = (__bf16)hn;
                if (hf) hf[off] = hn;
            }
        }
    }
}

// ---------------------------------------------------------------------------
// Tiled fp32 GEMM: C[M,N] = A[M,K] @ B[K,N] + bias. BM=BN=64, BK=16.
// (used only for the big head GEMM; M/64 x N/64 blocks)
// ---------------------------------------------------------------------------
__global__ __launch_bounds__(256) void gemm_nn(
    const float* __restrict__ A, int lda, const float* __restrict__ Bm, int ldb,
    const float* __restrict__ bias, float* __restrict__ C, int ldc,
    int M, int N, int K)
{
    __shared__ float As[16][68];
    __shared__ float Bs[16][68];
    int tid = threadIdx.x;
    int tx = tid & 15, ty = tid >> 4;
    int bm = blockIdx.y * 64, bn = blockIdx.x * 64;

    float acc[4][4] = {};

    for (int k0 = 0; k0 < K; k0 += 16) {
        for (int i = tid; i < 1024; i += 256) {
            int k = i & 15, m = i >> 4;
            As[k][m] = A[(size_t)(bm + m) * lda + k0 + k];
        }
        for (int i = tid; i < 1024; i += 256) {
            int n = i & 63, k = i >> 6;
            Bs[k][n] = Bm[(size_t)(k0 + k) * ldb + bn + n];
        }
        __syncthreads();
        #pragma unroll
        for (int kk = 0; kk < 16; kk++) {
            float4 a = *(const float4*)&As[kk][ty * 4];
            float4 b = *(const float4*)&Bs[kk][tx * 4];
            float av[4] = {a.x, a.y, a.z, a.w};
            float bv[4] = {b.x, b.y, b.z, b.w};
            #pragma unroll
            for (int i = 0; i < 4; i++)
                #pragma unroll
                for (int j = 0; j < 4; j++)
                    acc[i][j] += av[i] * bv[j];
        }
        __syncthreads();
    }

    #pragma unroll
    for (int i = 0; i < 4; i++) {
        int m = bm + ty * 4 + i;
        #pragma unroll
        for (int j = 0; j < 4; j++) {
            int n = bn + tx * 4 + j;
            C[(size_t)m * ldc + n] = acc[i][j] + (bias ? bias[n] : 0.f);
        }
    }
}

// ---------------------------------------------------------------------------
// Split-K fp32 GEMM for the small weight-collapse products (latency fix):
// P[s][M][N] partials, grid (N/64, M/64, SK), each slice covers K/SK.
// ---------------------------------------------------------------------------
__global__ __launch_bounds__(256) void gemm_nn_sk(
    const float* __restrict__ A, int lda, const float* __restrict__ Bm, int ldb,
    float* __restrict__ P, int M, int N, int K)
{
    __shared__ float As[16][68];
    __shared__ float Bs[16][68];
    int tid = threadIdx.x;
    int tx = tid & 15, ty = tid >> 4;
    int bm = blockIdx.y * 64, bn = blockIdx.x * 64;
    int klen = K / SK;
    int kbeg = blockIdx.z * klen;

    float acc[4][4] = {};

    for (int k0 = kbeg; k0 < kbeg + klen; k0 += 16) {
        for (int i = tid; i < 1024; i += 256) {
            int k = i & 15, m = i >> 4;
            As[k][m] = A[(size_t)(bm + m) * lda + k0 + k];
        }
        for (int i = tid; i < 1024; i += 256) {
            int n = i & 63, k = i >> 6;
            Bs[k][n] = Bm[(size_t)(k0 + k) * ldb + bn + n];
        }
        __syncthreads();
        #pragma unroll
        for (int kk = 0; kk < 16; kk++) {
            float4 a = *(const float4*)&As[kk][ty * 4];
            float4 b = *(const float4*)&Bs[kk][tx * 4];
            float av[4] = {a.x, a.y, a.z, a.w};
            float bv[4] = {b.x, b.y, b.z, b.w};
            #pragma unroll
            for (int i = 0; i < 4; i++)
                #pragma unroll
                for (int j = 0; j < 4; j++)
                    acc[i][j] += av[i] * bv[j];
        }
        __syncthreads();
    }

    float* Pd = P + (size_t)blockIdx.z * M * N;
    #pragma unroll
    for (int i = 0; i < 4; i++) {
        int m = bm + ty * 4 + i;
        #pragma unroll
        for (int j = 0; j < 4; j++) {
            int n = bn + tx * 4 + j;
            Pd[(size_t)m * N + n] = acc[i][j];
        }
    }
}

__global__ __launch_bounds__(256) void reduce_sk(
    const float* __restrict__ P, int MN, float* __restrict__ C)
{
    int i = blockIdx.x * 256 + threadIdx.x;
    if (i >= MN) return;
    float a = 0.f;
    #pragma unroll
    for (int s = 0; s < SK; s++) a += P[(size_t)s * MN + i];
    C[i] = a;
}

// ---------------------------------------------------------------------------
// vecmat: outv[n] = bias[n] + sum_k v[k] * M[k*ldb + n]
// ---------------------------------------------------------------------------
__global__ __launch_bounds__(256) void vecmat(
    const float* __restrict__ v, const float* __restrict__ M, int ldb, int K,
    const float* __restrict__ bias, float* __restrict__ outv)
{
    __shared__ float red[4][64];
    int l = threadIdx.x & 63;
    int w = threadIdx.x >> 6;
    int n = blockIdx.x * 64 + l;
    int kpw = K >> 2;
    int k0 = w * kpw;

    float p[8] = {};
    for (int k = k0; k < k0 + kpw; k += 8) {
        #pragma unroll
        for (int u = 0; u < 8; u++)
            p[u] += v[k + u] * M[(size_t)(k + u) * ldb + n];
    }
    red[w][l] = ((p[0] + p[1]) + (p[2] + p[3])) + ((p[4] + p[5]) + (p[6] + p[7]));
    __syncthreads();
    if (w == 0)
        outv[n] = red[0][l] + red[1][l] + red[2][l] + red[3][l]
                + (bias ? bias[n] : 0.f);
}

// ---------------------------------------------------------------------------
// Small helpers
// ---------------------------------------------------------------------------
__global__ void add_vec(const float* __restrict__ a, const float* __restrict__ b,
                        float* __restrict__ c, int n)
{
    int i = blockIdx.x * 256 + threadIdx.x;
    if (i < n) c[i] = a[i] + b[i];
}

// pack Wc0 [1024][320] bf16 = [Wih0 (59, pad to 64) | Whh0 (256)]
__global__ void pack_w0(const float* __restrict__ Wih, const float* __restrict__ Whh,
                        __bf16* __restrict__ Wc)
{
    int idx = blockIdx.x * 256 + threadIdx.x;
    if (idx >= 1024 * 320) return;
    int n = idx / 320, k = idx % 320;
    float v = (k < 59) ? Wih[(size_t)n * 59 + k]
            : (k < 64) ? 0.f
                       : Whh[(size_t)n * 256 + (k - 64)];
    Wc[idx] = (__bf16)v;
}

// pack Wc1 [1024][512] bf16 = [Wih1 (256) | Whh1 (256)]
__global__ void pack_w1(const float* __restrict__ Wih, const float* __restrict__ Whh,
                        __bf16* __restrict__ Wc)
{
    int idx = blockIdx.x * 256 + threadIdx.x;
    if (idx >= 1024 * 512) return;
    int n = idx / 512, k = idx % 512;
    float v = (k < 256) ? Wih[(size_t)n * 256 + k] : Whh[(size_t)n * 256 + (k - 256)];
    Wc[idx] = (__bf16)v;
}

// ---------------------------------------------------------------------------
extern "C" void kernel_launch(void* const* d_in, const int* in_sizes, int n_in,
                              void* d_out, int out_size, void* d_ws, size_t ws_size,
                              hipStream_t stream)
{
    const int*   region_idx = (const int*)d_in[0];
    const int*   poi_idx    = (const int*)d_in[1];
    const int*   car_idx    = (const int*)d_in[2];
    const int*   week_idx   = (const int*)d_in[3];
    const int*   time_idx   = (const int*)d_in[4];
    const float* coords     = (const float*)d_in[5];
    const float* region_tbl = (const float*)d_in[6];
    const float* poi_tbl    = (const float*)d_in[7];
    const float* car_tbl    = (const float*)d_in[8];
    const float* week_tbl   = (const float*)d_in[9];
    const float* time_tbl   = (const float*)d_in[10];
    const float* W_rp   = (const float*)d_in[11];
    const float* b_rp   = (const float*)d_in[12];
    const float* W_co   = (const float*)d_in[13];
    const float* b_co   = (const float*)d_in[14];
    const float* conv_w = (const float*)d_in[15];
    const float* conv_b = (const float*)d_in[16];
    const float* Wih0 = (const float*)d_in[17];
    const float* Whh0 = (const float*)d_in[18];
    const float* bih0 = (const float*)d_in[19];
    const float* bhh0 = (const float*)d_in[20];
    const float* Wih1 = (const float*)d_in[21];
    const float* Whh1 = (const float*)d_in[22];
    const float* bih1 = (const float*)d_in[23];
    const float* bhh1 = (const float*)d_in[24];
    const float* W1 = (const float*)d_in[25];
    const float* b1 = (const float*)d_in[26];
    const float* W2 = (const float*)d_in[27];
    const float* b2 = (const float*)d_in[28];
    const float* W3 = (const float*)d_in[29];
    const float* b3 = (const float*)d_in[30];
    float* out = (float*)d_out;

    // ---- workspace layout (~113 MB) ----
    char* ws = (char*)d_ws;
    size_t off = 0;
    auto alloc = [&](size_t bytes) -> char* {
        char* p = ws + off;
        off = (off + bytes + 255) & ~(size_t)255;
        return p;
    };
    __bf16* Xp   = (__bf16*)alloc((size_t)B_SZ * 8 * 64 * 2);   // 16.8 MB
    __bf16* h0b  = (__bf16*)alloc((size_t)B_SZ * HID * 2);      // 8.4 MB
    __bf16* h1b  = (__bf16*)alloc((size_t)B_SZ * HID * 2);      // 8.4 MB
    float*  c0   = (float*)alloc((size_t)B_SZ * HID * 4);       // 16.8 MB
    float*  c1   = (float*)alloc((size_t)B_SZ * HID * 4);       // 16.8 MB
    float*  h1f  = (float*)alloc((size_t)B_SZ * HID * 4);       // 16.8 MB
    __bf16* Wc0  = (__bf16*)alloc(1024 * 320 * 2);
    __bf16* Wc1  = (__bf16*)alloc(1024 * 512 * 2);
    float*  T1    = (float*)alloc(256 * 1024 * 4);
    float*  tb1   = (float*)alloc(1024 * 4);
    float*  Wcomb = (float*)alloc(256 * 512 * 4);
    float*  bcomb = (float*)alloc(512 * 4);
    float*  bias0 = (float*)alloc(1024 * 4);
    float*  bias1 = (float*)alloc(1024 * 4);
    float*  Psk   = (float*)alloc((size_t)SK * 256 * 1024 * 4); // 16.8 MB partials
    (void)ws_size;

    // ---- weight prep ----
    pack_w0<<<(1024 * 320 + 255) / 256, 256, 0, stream>>>(Wih0, Whh0, Wc0);
    pack_w1<<<(1024 * 512 + 255) / 256, 256, 0, stream>>>(Wih1, Whh1, Wc1);
    add_vec<<<4, 256, 0, stream>>>(bih0, bhh0, bias0, 1024);
    add_vec<<<4, 256, 0, stream>>>(bih1, bhh1, bias1, 1024);

    // ---- collapse head via split-K: Wcomb = W1@W2@W3 ----
    gemm_nn_sk<<<dim3(16, 4, SK), 256, 0, stream>>>(W1, 512, W2, 1024, Psk, 256, 1024, 512);
    reduce_sk<<<(256 * 1024 + 255) / 256, 256, 0, stream>>>(Psk, 256 * 1024, T1);
    vecmat<<<16, 256, 0, stream>>>(b1, W2, 1024, 512, b2, tb1);
    gemm_nn_sk<<<dim3(8, 4, SK), 256, 0, stream>>>(T1, 1024, W3, 512, Psk, 256, 512, 1024);
    reduce_sk<<<(256 * 512 + 255) / 256, 256, 0, stream>>>(Psk, 256 * 512, Wcomb);
    vecmat<<<8, 256, 0, stream>>>(tb1, W3, 512, 1024, b3, bcomb);

    // ---- features -> Xp bf16 ----
    feature_kernel<<<B_SZ / FB_SAMPLES, 256, 0, stream>>>(
        region_idx, poi_idx, car_idx, week_idx, time_idx, coords,
        region_tbl, poi_tbl, car_tbl, week_tbl, time_tbl,
        W_rp, b_rp, W_co, b_co, conv_w, conv_b, Xp);

    // ---- LSTM: both layers interleaved per timestep, full batch ----
    dim3 lstm_grid(4, B_SZ / 128);
    for (int t = 0; t < T_CONV; t++) {
        // layer 0: A = [Xp_t (64) | h0_prev (256)], W = Wc0 [1024][320]
        lstm_fused<<<lstm_grid, 256, 0, stream>>>(
            Xp + (size_t)t * 64, 8 * 64, 64,
            h0b, HID,
            Wc0, 320, bias0, c0, h0b, nullptr,
            t == 0 ? 2 : 10, t == 0);

        // layer 1: A = [h0_t (256) | h1_prev (256)], W = Wc1 [1024][512]
        lstm_fused<<<lstm_grid, 256, 0, stream>>>(
            h0b, HID, 256,
            h1b, HID,
            Wc1, 512, bias1, c1, h1b, (t == T_CONV - 1) ? h1f : nullptr,
            t == 0 ? 8 : 16, t == 0);
    }

    // ---- collapsed head: out = h1f @ Wcomb + bcomb (fp32) ----
    gemm_nn<<<dim3(512 / 64, B_SZ / 64), 256, 0, stream>>>(
        h1f, HID, Wcomb, 512, bcomb, out, 512, B_SZ, 512, HID);
}